// Round 7
// baseline (192.780 us; speedup 1.0000x reference)
//
#include <hip/hip_runtime.h>
#include <stdint.h>

#define DIM 768
#define NHEAD 12
#define HD 64
#define B_ 8
#define SPEC 4
#define T_ 8
#define AP 196
#define VP 196
#define MQ (VP*T_)      // 1568
#define NKV (AP*SPEC)   // 784
#define QSCALE 0.1803368801111618f   // 0.125 * log2(e): softmax done in exp2 domain

typedef short bf16x8 __attribute__((ext_vector_type(8)));
typedef short bf16x4 __attribute__((ext_vector_type(4)));
typedef float f32x4 __attribute__((ext_vector_type(4)));

__device__ __forceinline__ ushort f2bf(float f) {
    union { float f; unsigned u; } v; v.f = f;
    unsigned u = v.u;
    return (ushort)((u + 0x7fffu + ((u >> 16) & 1u)) >> 16);
}

__device__ __forceinline__ float fexp2(float x) {
    float r;
    asm("v_exp_f32 %0, %1" : "=v"(r) : "v"(x));
    return r;   // 2^x
}

// pack two f32 -> {lo = trunc-bf16(a), hi = trunc-bf16(b)} (proven bit-op path)
__device__ __forceinline__ unsigned pk2(float a, float b) {
    union { float f; unsigned u; } ua, ub; ua.f = a; ub.f = b;
    return (ub.u & 0xFFFF0000u) | (ua.u >> 16);
}

typedef const __attribute__((address_space(1))) void GV;
typedef __attribute__((address_space(3))) void LV;
__device__ __forceinline__ void gload16(const void* g, void* l) {
    __builtin_amdgcn_global_load_lds((GV*)g, (LV*)l, 16, 0, 0);
}

// ---------------- merged prep kernel (range-dispatched) ----------------

__global__ void prep_all_k(const float* __restrict__ t_x,
                           const float* __restrict__ vsp,
                           const float* __restrict__ vtp,
                           const float* __restrict__ s_x,
                           const float* __restrict__ csp,
                           const float* __restrict__ ctp,
                           const float* __restrict__ Wq,
                           const float* __restrict__ Wkv,
                           const float* __restrict__ Wpj,
                           ushort* __restrict__ qin,
                           ushort* __restrict__ sb,
                           ushort* __restrict__ wqb,
                           ushort* __restrict__ wkvb,
                           ushort* __restrict__ wpjb,
                           float* __restrict__ out) {
    int bid = blockIdx.x;
    if (bid < 9408) {
        int i = bid * 256 + threadIdx.x;
        int d4 = i % (DIM / 4);
        int rest = i / (DIM / 4);
        int m = rest % MQ;
        int b = rest / MQ;
        int vp = m >> 3, t = m & 7;
        const float4 a  = *(const float4*)(t_x + ((size_t)(1 + vp) * (B_ * T_) + b * T_ + t) * DIM + d4 * 4);
        const float4 p1 = *(const float4*)(vsp + (size_t)vp * DIM + d4 * 4);
        const float4 p2 = *(const float4*)(vtp + (size_t)t * DIM + d4 * 4);
        ushort4 r;
        r.x = f2bf(a.x + p1.x + p2.x);
        r.y = f2bf(a.y + p1.y + p2.y);
        r.z = f2bf(a.z + p1.z + p2.z);
        r.w = f2bf(a.w + p1.w + p2.w);
        *(ushort4*)(qin + ((size_t)(b * MQ + m)) * DIM + d4 * 4) = r;
    } else if (bid < 14112) {
        int i = (bid - 9408) * 256 + threadIdx.x;
        int d4 = i % (DIM / 4);
        int rest = i / (DIM / 4);
        int n = rest % NKV;
        int b = rest / NKV;
        int ap = n >> 2, spec = n & 3;
        const float4 a  = *(const float4*)(s_x + ((size_t)ap * (B_ * SPEC) + b * SPEC + spec) * DIM + d4 * 4);
        const float4 p1 = *(const float4*)(csp + (size_t)ap * DIM + d4 * 4);
        const float4 p2 = *(const float4*)(ctp + (size_t)spec * DIM + d4 * 4);
        ushort4 r;
        r.x = f2bf(a.x + p1.x + p2.x);
        r.y = f2bf(a.y + p1.y + p2.y);
        r.z = f2bf(a.z + p1.z + p2.z);
        r.w = f2bf(a.w + p1.w + p2.w);
        *(ushort4*)(sb + ((size_t)(b * NKV + n)) * DIM + d4 * 4) = r;
    } else if (bid < 16416) {
        const float* src; ushort* dst; int i;
        if (bid < 14688)      { src = Wq;  dst = wqb;  i = (bid - 14112) * 256 + threadIdx.x; }
        else if (bid < 15840) { src = Wkv; dst = wkvb; i = (bid - 14688) * 256 + threadIdx.x; }
        else                  { src = Wpj; dst = wpjb; i = (bid - 15840) * 256 + threadIdx.x; }
        float4 v = *(const float4*)(src + (size_t)i * 4);
        ushort4 r;
        r.x = f2bf(v.x); r.y = f2bf(v.y); r.z = f2bf(v.z); r.w = f2bf(v.w);
        *(ushort4*)(dst + (size_t)i * 4) = r;
    } else {
        int i = (bid - 16416) * 256 + threadIdx.x;
        *(float4*)(out + (size_t)i * 4) = *(const float4*)(t_x + (size_t)i * 4);
    }
}

// ---------------- GEMM core (128x128 tile, BK=32, 4 waves, bf16 MFMA) ----------------

template <int MODE>
__device__ __forceinline__ void gemm_body(ushort* As, ushort* Bs,
                                          const ushort* __restrict__ A,
                                          const ushort* __restrict__ Bw,
                                          const float* __restrict__ bias,
                                          ushort* __restrict__ out_a,
                                          ushort* __restrict__ out_b,
                                          float* __restrict__ out_f,
                                          int m0, int n0) {
    const int tid = threadIdx.x;
    const int lane = tid & 63, wid = tid >> 6;
    const int wm = wid >> 1, wn = wid & 1;
    const int lr = lane & 15, hi = lane >> 4;

    const int srow = wid * 32 + (lane >> 2);
    const int scolb = (lane & 3) * 16;
    const char* gA = (const char*)A + ((size_t)(m0 + srow) * DIM) * 2 + scolb;
    const char* gB = (const char*)Bw + ((size_t)(n0 + srow) * DIM) * 2 + scolb;
    const size_t radv = (size_t)16 * DIM * 2;
    char* lA = (char*)As + wid * 2048;
    char* lB = (char*)Bs + wid * 2048;

    f32x4 acc[4][4] = {};

    for (int k0 = 0; k0 < DIM; k0 += 32) {
        size_t ko = (size_t)k0 * 2;
        gload16(gA + ko,        lA);
        gload16(gA + ko + radv, lA + 1024);
        gload16(gB + ko,        lB);
        gload16(gB + ko + radv, lB + 1024);
        __syncthreads();
        bf16x8 af[4], bfr[4];
#pragma unroll
        for (int x = 0; x < 4; ++x) {
            af[x]  = *(const bf16x8*)&As[(wm * 64 + x * 16 + lr) * 32 + hi * 8];
            bfr[x] = *(const bf16x8*)&Bs[(wn * 64 + x * 16 + lr) * 32 + hi * 8];
        }
#pragma unroll
        for (int mi = 0; mi < 4; ++mi)
#pragma unroll
            for (int ni = 0; ni < 4; ++ni)
                acc[mi][ni] = __builtin_amdgcn_mfma_f32_16x16x32_bf16(af[mi], bfr[ni], acc[mi][ni], 0, 0, 0);
        __syncthreads();
    }

#pragma unroll
    for (int mi = 0; mi < 4; ++mi) {
#pragma unroll
        for (int ni = 0; ni < 4; ++ni) {
            int gn = n0 + wn * 64 + ni * 16 + lr;
            float bv = bias[gn];
            if (MODE == 1 && gn >= DIM) {
                int o2 = gn - DIM;
                int hh = o2 >> 6, d = o2 & 63;
                int gm0 = m0 + wm * 64 + mi * 16 + hi * 4;
                int b = gm0 / NKV, n = gm0 % NKV;
                ushort4 pk;
                pk.x = f2bf(acc[mi][ni][0] + bv);
                pk.y = f2bf(acc[mi][ni][1] + bv);
                pk.z = f2bf(acc[mi][ni][2] + bv);
                pk.w = f2bf(acc[mi][ni][3] + bv);
                *(ushort4*)&out_b[(((size_t)(b * NHEAD + hh)) * HD + d) * NKV + n] = pk;
                continue;
            }
#pragma unroll
            for (int r = 0; r < 4; ++r) {
                int gm = m0 + wm * 64 + mi * 16 + hi * 4 + r;
                float val = acc[mi][ni][r] + bv;
                if (MODE == 0) {
                    int b = gm / MQ, m = gm % MQ;
                    int hh = gn >> 6, d = gn & 63;
                    out_a[(((size_t)(b * NHEAD + hh)) * MQ + m) * HD + d] = f2bf(val * QSCALE);
                } else if (MODE == 1) {
                    int b = gm / NKV, n = gm % NKV;
                    int hh = gn >> 6, d = gn & 63;
                    out_a[(((size_t)(b * NHEAD + hh)) * NKV + n) * HD + d] = f2bf(val);
                } else {
                    int b = gm / MQ, m = gm % MQ;
                    int vp = m >> 3, tt = m & 7;
                    out_f[((size_t)(1 + vp) * (B_ * T_) + b * T_ + tt) * DIM + gn] = val;
                }
            }
        }
    }
}

// merged Q-GEMM (588 blocks) + KV-GEMM (588 blocks)
__global__ __launch_bounds__(256) void gemm_qkv_k(const ushort* __restrict__ qin,
                                                  const ushort* __restrict__ sbuf,
                                                  const ushort* __restrict__ wqb,
                                                  const ushort* __restrict__ wkvb,
                                                  const float* __restrict__ qb,
                                                  const float* __restrict__ kvb,
                                                  ushort* __restrict__ qs,
                                                  ushort* __restrict__ kb,
                                                  ushort* __restrict__ vtb) {
    __shared__ __align__(16) ushort As[128 * 32];
    __shared__ __align__(16) ushort Bs[128 * 32];
    int bid = blockIdx.x;
    if (bid < 588) {
        int by = bid / 6, bx = bid % 6;
        gemm_body<0>(As, Bs, qin, wqb, qb, qs, nullptr, nullptr, by * 128, bx * 128);
    } else {
        int b2 = bid - 588;
        int by = b2 / 12, bx = b2 % 12;
        gemm_body<1>(As, Bs, sbuf, wkvb, kvb, kb, vtb, nullptr, by * 128, bx * 128);
    }
}

__global__ __launch_bounds__(256) void gemm_proj_k(const ushort* __restrict__ ob,
                                                   const ushort* __restrict__ wpjb,
                                                   const float* __restrict__ pjb,
                                                   float* __restrict__ out) {
    __shared__ __align__(16) ushort As[128 * 32];
    __shared__ __align__(16) ushort Bs[128 * 32];
    gemm_body<2>(As, Bs, ob, wpjb, pjb, nullptr, nullptr, out, blockIdx.y * 128, blockIdx.x * 128);
}

// ---------------- attention (swapped-operand, LDS-free, all-x32 MFMA) ----------------
// 1D grid of 2400 blocks (96 bh x 25 mb), bh-major: bid = mb*96 + bh keeps all
// blocks of one (b,h) on ONE XCD (K/V L2-resident, proven round 5: FETCH 96->23MB).
// 128 thr = 2 waves; each wave owns 2 Q-tiles (32 rows) -> 4698 active waves
// (~4/SIMD resident at ~110 VGPR) for latency hiding. Last block per bh: wave 0
// covers tiles 96-97, wave 1 exits.
// QK^T swapped: S^T = mfma(K, Q): lane (hi,lr) holds P[m=lr][n = nb+16*slice+4*hi+r].
// PV via 16x16x32 mfma, k<->n bijection n(8*hi+j) = 16*(j>=4) + 4*hi + (j&3).
// No-max softmax in exp2 domain; row sums lane-local, reduced once at the end.

template <int NT>
__device__ __forceinline__ void attn_wave(const ushort* __restrict__ q,
                                          const ushort* __restrict__ kp,
                                          const ushort* __restrict__ vtp,
                                          ushort* __restrict__ obuf,
                                          int bh, int b, int h, int m0, int lane) {
    const int lr = lane & 15, hi = lane >> 4;

    bf16x8 qa0[NT], qa1[NT];
#pragma unroll
    for (int t = 0; t < NT; ++t) {
        const ushort* qp = q + ((size_t)bh * MQ + m0 + t * 16 + lr) * HD;
        qa0[t] = *(const bf16x8*)(qp + hi * 8);
        qa1[t] = *(const bf16x8*)(qp + 32 + hi * 8);
    }

    f32x4 oacc[NT][4] = {};
    float lsum[NT] = {};

    // K buffers: [0]=sliceA d0-31, [1]=sliceA d32-63, [2]=sliceB d0-31, [3]=sliceB d32-63
    bf16x8 kA[4], kB[4];
    {
        const ushort* ka = kp + (size_t)lr * HD + hi * 8;
        kA[0] = *(const bf16x8*)ka;
        kA[1] = *(const bf16x8*)(ka + 32);
        const ushort* k2 = ka + 16 * HD;
        kA[2] = *(const bf16x8*)k2;
        kA[3] = *(const bf16x8*)(k2 + 32);
    }

    auto gbody = [&](bf16x8* kc, bf16x8* kn, int g) {
        const int nb = g * 32;
        // V loads for this group (used after QK+softmax)
        bf16x4 va[4], vb[4];
#pragma unroll
        for (int db = 0; db < 4; ++db) {
            const ushort* vp = vtp + (size_t)(db * 16 + lr) * NKV + nb + hi * 4;
            va[db] = *(const bf16x4*)vp;
            vb[db] = *(const bf16x4*)(vp + 16);
        }
        // prefetch K group g+1 (clamped; clamped sliceB only feeds the unused tail regs)
        {
            int np = nb + 32;
            int npB = (np + 16 > 768) ? 768 : np + 16;
            const ushort* ka = kp + (size_t)(np + lr) * HD + hi * 8;
            kn[0] = *(const bf16x8*)ka;
            kn[1] = *(const bf16x8*)(ka + 32);
            const ushort* k2 = kp + (size_t)(npB + lr) * HD + hi * 8;
            kn[2] = *(const bf16x8*)k2;
            kn[3] = *(const bf16x8*)(k2 + 32);
        }
#pragma unroll
        for (int t = 0; t < NT; ++t) {
            f32x4 sA = {}, sB = {};
            sA = __builtin_amdgcn_mfma_f32_16x16x32_bf16(kc[0], qa0[t], sA, 0, 0, 0);
            sA = __builtin_amdgcn_mfma_f32_16x16x32_bf16(kc[1], qa1[t], sA, 0, 0, 0);
            sB = __builtin_amdgcn_mfma_f32_16x16x32_bf16(kc[2], qa0[t], sB, 0, 0, 0);
            sB = __builtin_amdgcn_mfma_f32_16x16x32_bf16(kc[3], qa1[t], sB, 0, 0, 0);
            float eA0 = fexp2(sA[0]), eA1 = fexp2(sA[1]), eA2 = fexp2(sA[2]), eA3 = fexp2(sA[3]);
            float eB0 = fexp2(sB[0]), eB1 = fexp2(sB[1]), eB2 = fexp2(sB[2]), eB3 = fexp2(sB[3]);
            lsum[t] += ((eA0 + eA1) + (eA2 + eA3)) + ((eB0 + eB1) + (eB2 + eB3));
            union { uint4 w; bf16x8 v; } pk;
            pk.w.x = pk2(eA0, eA1);
            pk.w.y = pk2(eA2, eA3);
            pk.w.z = pk2(eB0, eB1);
            pk.w.w = pk2(eB2, eB3);
#pragma unroll
            for (int db = 0; db < 4; ++db) {
                union { struct { bf16x4 lo, hi_; } s; bf16x8 v; } vf;
                vf.s.lo = va[db]; vf.s.hi_ = vb[db];
                oacc[t][db] = __builtin_amdgcn_mfma_f32_16x16x32_bf16(pk.v, vf.v, oacc[t][db], 0, 0, 0);
            }
        }
    };

    for (int g = 0; g < 24; g += 2) {
        gbody(kA, kB, g);
        gbody(kB, kA, g + 1);
    }

    // tail: nb = 768, rows 768..783 (sliceA only; A-frag elements 4-7 zeroed)
    {
        bf16x4 va[4];
#pragma unroll
        for (int db = 0; db < 4; ++db)
            va[db] = *(const bf16x4*)(vtp + (size_t)(db * 16 + lr) * NKV + 768 + hi * 4);
#pragma unroll
        for (int t = 0; t < NT; ++t) {
            f32x4 sA = {};
            sA = __builtin_amdgcn_mfma_f32_16x16x32_bf16(kA[0], qa0[t], sA, 0, 0, 0);
            sA = __builtin_amdgcn_mfma_f32_16x16x32_bf16(kA[1], qa1[t], sA, 0, 0, 0);
            float eA0 = fexp2(sA[0]), eA1 = fexp2(sA[1]), eA2 = fexp2(sA[2]), eA3 = fexp2(sA[3]);
            lsum[t] += (eA0 + eA1) + (eA2 + eA3);
            union { uint4 w; bf16x8 v; } pk;
            pk.w.x = pk2(eA0, eA1);
            pk.w.y = pk2(eA2, eA3);
            pk.w.z = 0;
            pk.w.w = 0;
#pragma unroll
            for (int db = 0; db < 4; ++db) {
                union { struct { bf16x4 lo, hi_; } s; bf16x8 v; } vf;
                vf.s.lo = va[db]; vf.s.hi_ = va[db];   // hi half multiplied by 0
                oacc[t][db] = __builtin_amdgcn_mfma_f32_16x16x32_bf16(pk.v, vf.v, oacc[t][db], 0, 0, 0);
            }
        }
    }

    // epilogue: lane (hi,lr) has partial row-sum for m=lr; reduce over hi-groups,
    // broadcast to the output fragment rows (m = 4*hi+r), normalize, store.
#pragma unroll
    for (int t = 0; t < NT; ++t) {
        float sum = lsum[t];
        sum += __shfl_xor(sum, 16);
        sum += __shfl_xor(sum, 32);
        float inv = 1.0f / sum;   // valid for row m = lr
#pragma unroll
        for (int r = 0; r < 4; ++r) {
            float invr = __shfl(inv, hi * 4 + r);
            int m = m0 + t * 16 + hi * 4 + r;
            ushort* op = obuf + ((size_t)b * MQ + m) * DIM + h * HD;
#pragma unroll
            for (int db = 0; db < 4; ++db)
                op[db * 16 + lr] = f2bf(oacc[t][db][r] * invr);
        }
    }
}

__global__ __launch_bounds__(128) void attn_k(const ushort* __restrict__ q,
                                              const ushort* __restrict__ kbuf,
                                              const ushort* __restrict__ vt,
                                              ushort* __restrict__ obuf) {
    const int lane = threadIdx.x & 63, wid = threadIdx.x >> 6;
    const int bid = blockIdx.x;
    const int bh = bid % 96;           // bh-major: all mb of one bh share bid%8 -> one XCD
    const int mb = bid / 96;
    const int b = bh / NHEAD, h = bh % NHEAD;
    const int m0 = mb * 64 + wid * 32; // 2 tiles of 16 rows per wave
    if (m0 >= MQ) return;              // wave 1 of mb=24
    const ushort* kp  = kbuf + (size_t)bh * NKV * HD;
    const ushort* vtp = vt + (size_t)bh * HD * NKV;
    attn_wave<2>(q, kp, vtp, obuf, bh, b, h, m0, lane);
}

// ---------------- launch ----------------

extern "C" void kernel_launch(void* const* d_in, const int* in_sizes, int n_in,
                              void* d_out, int out_size, void* d_ws, size_t ws_size,
                              hipStream_t stream) {
    const float* s_x  = (const float*)d_in[0];
    const float* t_x  = (const float*)d_in[1];
    const float* csp  = (const float*)d_in[2];
    const float* ctp  = (const float*)d_in[3];
    const float* vsp  = (const float*)d_in[4];
    const float* vtp  = (const float*)d_in[5];
    const float* Wq   = (const float*)d_in[6];
    const float* qb   = (const float*)d_in[7];
    const float* Wkv  = (const float*)d_in[8];
    const float* kvb  = (const float*)d_in[9];
    const float* Wpj  = (const float*)d_in[10];
    const float* pjb  = (const float*)d_in[11];
    float* out = (float*)d_out;

    ushort* w = (ushort*)d_ws;
    ushort* qin  = w; w += (size_t)B_ * MQ * DIM;
    ushort* sb   = w; w += (size_t)B_ * NKV * DIM;
    ushort* wqb  = w; w += (size_t)DIM * DIM;
    ushort* wkvb = w; w += (size_t)2 * DIM * DIM;
    ushort* wpjb = w; w += (size_t)DIM * DIM;
    ushort* qs   = w; w += (size_t)B_ * NHEAD * MQ * HD;
    ushort* kb   = w; w += (size_t)B_ * NHEAD * NKV * HD;
    ushort* vtb  = w; w += (size_t)B_ * NHEAD * HD * NKV;
    ushort* ob   = w; w += (size_t)B_ * MQ * DIM;

    prep_all_k<<<16464, 256, 0, stream>>>(t_x, vsp, vtp, s_x, csp, ctp,
                                          Wq, Wkv, Wpj,
                                          qin, sb, wqb, wkvb, wpjb, out);

    gemm_qkv_k<<<588 + 588, 256, 0, stream>>>(qin, sb, wqb, wkvb, qb, kvb, qs, kb, vtb);

    attn_k<<<2400, 128, 0, stream>>>(qs, kb, vtb, ob);

    gemm_proj_k<<<dim3(DIM / 128, B_ * MQ / 128), 256, 0, stream>>>(ob, wpjb, pjb, out);
}

// Round 8
// 166.141 us; speedup vs baseline: 1.1603x; 1.1603x over previous
//
#include <hip/hip_runtime.h>
#include <stdint.h>

#define DIM 768
#define NHEAD 12
#define HD 64
#define B_ 8
#define SPEC 4
#define T_ 8
#define AP 196
#define VP 196
#define MQ (VP*T_)      // 1568
#define NKV (AP*SPEC)   // 784
#define QSCALE 0.1803368801111618f   // 0.125 * log2(e): softmax done in exp2 domain

typedef short bf16x8 __attribute__((ext_vector_type(8)));
typedef short bf16x4 __attribute__((ext_vector_type(4)));
typedef float f32x4 __attribute__((ext_vector_type(4)));

__device__ __forceinline__ ushort f2bf(float f) {
    union { float f; unsigned u; } v; v.f = f;
    unsigned u = v.u;
    return (ushort)((u + 0x7fffu + ((u >> 16) & 1u)) >> 16);
}

__device__ __forceinline__ float fexp2(float x) {
    float r;
    asm("v_exp_f32 %0, %1" : "=v"(r) : "v"(x));
    return r;   // 2^x
}

// pack two f32 -> {lo = trunc-bf16(a), hi = trunc-bf16(b)} (proven bit-op path)
__device__ __forceinline__ unsigned pk2(float a, float b) {
    union { float f; unsigned u; } ua, ub; ua.f = a; ub.f = b;
    return (ub.u & 0xFFFF0000u) | (ua.u >> 16);
}

typedef const __attribute__((address_space(1))) void GV;
typedef __attribute__((address_space(3))) void LV;
__device__ __forceinline__ void gload16(const void* g, void* l) {
    __builtin_amdgcn_global_load_lds((GV*)g, (LV*)l, 16, 0, 0);
}

// ---------------- merged prep kernel (range-dispatched) ----------------

__global__ void prep_all_k(const float* __restrict__ t_x,
                           const float* __restrict__ vsp,
                           const float* __restrict__ vtp,
                           const float* __restrict__ s_x,
                           const float* __restrict__ csp,
                           const float* __restrict__ ctp,
                           const float* __restrict__ Wq,
                           const float* __restrict__ Wkv,
                           const float* __restrict__ Wpj,
                           ushort* __restrict__ qin,
                           ushort* __restrict__ sb,
                           ushort* __restrict__ wqb,
                           ushort* __restrict__ wkvb,
                           ushort* __restrict__ wpjb,
                           float* __restrict__ out) {
    int bid = blockIdx.x;
    if (bid < 9408) {
        int i = bid * 256 + threadIdx.x;
        int d4 = i % (DIM / 4);
        int rest = i / (DIM / 4);
        int m = rest % MQ;
        int b = rest / MQ;
        int vp = m >> 3, t = m & 7;
        const float4 a  = *(const float4*)(t_x + ((size_t)(1 + vp) * (B_ * T_) + b * T_ + t) * DIM + d4 * 4);
        const float4 p1 = *(const float4*)(vsp + (size_t)vp * DIM + d4 * 4);
        const float4 p2 = *(const float4*)(vtp + (size_t)t * DIM + d4 * 4);
        ushort4 r;
        r.x = f2bf(a.x + p1.x + p2.x);
        r.y = f2bf(a.y + p1.y + p2.y);
        r.z = f2bf(a.z + p1.z + p2.z);
        r.w = f2bf(a.w + p1.w + p2.w);
        *(ushort4*)(qin + ((size_t)(b * MQ + m)) * DIM + d4 * 4) = r;
    } else if (bid < 14112) {
        int i = (bid - 9408) * 256 + threadIdx.x;
        int d4 = i % (DIM / 4);
        int rest = i / (DIM / 4);
        int n = rest % NKV;
        int b = rest / NKV;
        int ap = n >> 2, spec = n & 3;
        const float4 a  = *(const float4*)(s_x + ((size_t)ap * (B_ * SPEC) + b * SPEC + spec) * DIM + d4 * 4);
        const float4 p1 = *(const float4*)(csp + (size_t)ap * DIM + d4 * 4);
        const float4 p2 = *(const float4*)(ctp + (size_t)spec * DIM + d4 * 4);
        ushort4 r;
        r.x = f2bf(a.x + p1.x + p2.x);
        r.y = f2bf(a.y + p1.y + p2.y);
        r.z = f2bf(a.z + p1.z + p2.z);
        r.w = f2bf(a.w + p1.w + p2.w);
        *(ushort4*)(sb + ((size_t)(b * NKV + n)) * DIM + d4 * 4) = r;
    } else if (bid < 16416) {
        const float* src; ushort* dst; int i;
        if (bid < 14688)      { src = Wq;  dst = wqb;  i = (bid - 14112) * 256 + threadIdx.x; }
        else if (bid < 15840) { src = Wkv; dst = wkvb; i = (bid - 14688) * 256 + threadIdx.x; }
        else                  { src = Wpj; dst = wpjb; i = (bid - 15840) * 256 + threadIdx.x; }
        float4 v = *(const float4*)(src + (size_t)i * 4);
        ushort4 r;
        r.x = f2bf(v.x); r.y = f2bf(v.y); r.z = f2bf(v.z); r.w = f2bf(v.w);
        *(ushort4*)(dst + (size_t)i * 4) = r;
    } else {
        int i = (bid - 16416) * 256 + threadIdx.x;
        *(float4*)(out + (size_t)i * 4) = *(const float4*)(t_x + (size_t)i * 4);
    }
}

// ---------------- GEMM core (128x128 tile, BK=32, 4 waves, bf16 MFMA) ----------------

template <int MODE>
__device__ __forceinline__ void gemm_body(ushort* As, ushort* Bs,
                                          const ushort* __restrict__ A,
                                          const ushort* __restrict__ Bw,
                                          const float* __restrict__ bias,
                                          ushort* __restrict__ out_a,
                                          ushort* __restrict__ out_b,
                                          float* __restrict__ out_f,
                                          int m0, int n0) {
    const int tid = threadIdx.x;
    const int lane = tid & 63, wid = tid >> 6;
    const int wm = wid >> 1, wn = wid & 1;
    const int lr = lane & 15, hi = lane >> 4;

    const int srow = wid * 32 + (lane >> 2);
    const int scolb = (lane & 3) * 16;
    const char* gA = (const char*)A + ((size_t)(m0 + srow) * DIM) * 2 + scolb;
    const char* gB = (const char*)Bw + ((size_t)(n0 + srow) * DIM) * 2 + scolb;
    const size_t radv = (size_t)16 * DIM * 2;
    char* lA = (char*)As + wid * 2048;
    char* lB = (char*)Bs + wid * 2048;

    f32x4 acc[4][4] = {};

    for (int k0 = 0; k0 < DIM; k0 += 32) {
        size_t ko = (size_t)k0 * 2;
        gload16(gA + ko,        lA);
        gload16(gA + ko + radv, lA + 1024);
        gload16(gB + ko,        lB);
        gload16(gB + ko + radv, lB + 1024);
        __syncthreads();
        bf16x8 af[4], bfr[4];
#pragma unroll
        for (int x = 0; x < 4; ++x) {
            af[x]  = *(const bf16x8*)&As[(wm * 64 + x * 16 + lr) * 32 + hi * 8];
            bfr[x] = *(const bf16x8*)&Bs[(wn * 64 + x * 16 + lr) * 32 + hi * 8];
        }
#pragma unroll
        for (int mi = 0; mi < 4; ++mi)
#pragma unroll
            for (int ni = 0; ni < 4; ++ni)
                acc[mi][ni] = __builtin_amdgcn_mfma_f32_16x16x32_bf16(af[mi], bfr[ni], acc[mi][ni], 0, 0, 0);
        __syncthreads();
    }

#pragma unroll
    for (int mi = 0; mi < 4; ++mi) {
#pragma unroll
        for (int ni = 0; ni < 4; ++ni) {
            int gn = n0 + wn * 64 + ni * 16 + lr;
            float bv = bias[gn];
            if (MODE == 1 && gn >= DIM) {
                int o2 = gn - DIM;
                int hh = o2 >> 6, d = o2 & 63;
                int gm0 = m0 + wm * 64 + mi * 16 + hi * 4;
                int b = gm0 / NKV, n = gm0 % NKV;
                ushort4 pk;
                pk.x = f2bf(acc[mi][ni][0] + bv);
                pk.y = f2bf(acc[mi][ni][1] + bv);
                pk.z = f2bf(acc[mi][ni][2] + bv);
                pk.w = f2bf(acc[mi][ni][3] + bv);
                *(ushort4*)&out_b[(((size_t)(b * NHEAD + hh)) * HD + d) * NKV + n] = pk;
                continue;
            }
#pragma unroll
            for (int r = 0; r < 4; ++r) {
                int gm = m0 + wm * 64 + mi * 16 + hi * 4 + r;
                float val = acc[mi][ni][r] + bv;
                if (MODE == 0) {
                    int b = gm / MQ, m = gm % MQ;
                    int hh = gn >> 6, d = gn & 63;
                    out_a[(((size_t)(b * NHEAD + hh)) * MQ + m) * HD + d] = f2bf(val * QSCALE);
                } else if (MODE == 1) {
                    int b = gm / NKV, n = gm % NKV;
                    int hh = gn >> 6, d = gn & 63;
                    out_a[(((size_t)(b * NHEAD + hh)) * NKV + n) * HD + d] = f2bf(val);
                } else {
                    int b = gm / MQ, m = gm % MQ;
                    int vp = m >> 3, tt = m & 7;
                    out_f[((size_t)(1 + vp) * (B_ * T_) + b * T_ + tt) * DIM + gn] = val;
                }
            }
        }
    }
}

// merged Q-GEMM (588 blocks) + KV-GEMM (588 blocks)
__global__ __launch_bounds__(256) void gemm_qkv_k(const ushort* __restrict__ qin,
                                                  const ushort* __restrict__ sbuf,
                                                  const ushort* __restrict__ wqb,
                                                  const ushort* __restrict__ wkvb,
                                                  const float* __restrict__ qb,
                                                  const float* __restrict__ kvb,
                                                  ushort* __restrict__ qs,
                                                  ushort* __restrict__ kb,
                                                  ushort* __restrict__ vtb) {
    __shared__ __align__(16) ushort As[128 * 32];
    __shared__ __align__(16) ushort Bs[128 * 32];
    int bid = blockIdx.x;
    if (bid < 588) {
        int by = bid / 6, bx = bid % 6;
        gemm_body<0>(As, Bs, qin, wqb, qb, qs, nullptr, nullptr, by * 128, bx * 128);
    } else {
        int b2 = bid - 588;
        int by = b2 / 12, bx = b2 % 12;
        gemm_body<1>(As, Bs, sbuf, wkvb, kvb, kb, vtb, nullptr, by * 128, bx * 128);
    }
}

__global__ __launch_bounds__(256) void gemm_proj_k(const ushort* __restrict__ ob,
                                                   const ushort* __restrict__ wpjb,
                                                   const float* __restrict__ pjb,
                                                   float* __restrict__ out) {
    __shared__ __align__(16) ushort As[128 * 32];
    __shared__ __align__(16) ushort Bs[128 * 32];
    gemm_body<2>(As, Bs, ob, wpjb, pjb, nullptr, nullptr, out, blockIdx.y * 128, blockIdx.x * 128);
}

// ---------------- attention (swapped-operand, LDS-free, all-x32 MFMA) ----------------
// 1D grid of 1344 blocks (96 bh x 14 mb), bh-major: bid = mb*96 + bh keeps all
// blocks of one (b,h) on ONE XCD (K/V L2-resident, proven round 5: FETCH 96->23MB).
// 128 thr = 2 waves; wave 0: NT=4 tiles, wave 1: NT=3 tiles (112 rows/block).
// NT=4/3 proven faster than NT=2 (R7 A/B: chain-parallelism + K/V amortization win).
// NEW vs R5: V double-buffered like K (full-group prefetch lead on ALL loads),
// tail reuses prefetched K(24)/V(24), s_setprio(1) around compute cluster (T5).
// QK^T swapped: S^T = mfma(K, Q): lane (hi,lr) holds P[m=lr][n = nb+16*slice+4*hi+r].
// PV via 16x16x32 mfma, k<->n bijection n(8*hi+j) = 16*(j>=4) + 4*hi + (j&3).
// No-max softmax in exp2 domain; row sums lane-local, reduced once at the end.

template <int NT>
__device__ __forceinline__ void attn_wave(const ushort* __restrict__ q,
                                          const ushort* __restrict__ kp,
                                          const ushort* __restrict__ vtp,
                                          ushort* __restrict__ obuf,
                                          int bh, int b, int h, int m0, int lane) {
    const int lr = lane & 15, hi = lane >> 4;

    bf16x8 qa0[NT], qa1[NT];
#pragma unroll
    for (int t = 0; t < NT; ++t) {
        const ushort* qp = q + ((size_t)bh * MQ + m0 + t * 16 + lr) * HD;
        qa0[t] = *(const bf16x8*)(qp + hi * 8);
        qa1[t] = *(const bf16x8*)(qp + 32 + hi * 8);
    }

    f32x4 oacc[NT][4] = {};
    float lsum[NT] = {};

    // double-buffered K and V registers
    bf16x8 kA[4], kB[4];
    bf16x4 vAa[4], vAb[4], vBa[4], vBb[4];
    {
        const ushort* ka = kp + (size_t)lr * HD + hi * 8;
        kA[0] = *(const bf16x8*)ka;
        kA[1] = *(const bf16x8*)(ka + 32);
        const ushort* k2 = ka + 16 * HD;
        kA[2] = *(const bf16x8*)k2;
        kA[3] = *(const bf16x8*)(k2 + 32);
#pragma unroll
        for (int db = 0; db < 4; ++db) {
            const ushort* vp = vtp + (size_t)(db * 16 + lr) * NKV + hi * 4;
            vAa[db] = *(const bf16x4*)vp;
            vAb[db] = *(const bf16x4*)(vp + 16);
        }
    }

    auto gbody = [&](bf16x8* kc, bf16x4* vca, bf16x4* vcb,
                     bf16x8* kn, bf16x4* vna, bf16x4* vnb, int g) {
        const int nb = g * 32;
        const int np = nb + 32;
        const int npB = (np + 16 > 768) ? 768 : np + 16;
        // prefetch K(g+1) and V(g+1) — consumed next gbody (full-group latency lead)
        {
            const ushort* ka = kp + (size_t)(np + lr) * HD + hi * 8;
            kn[0] = *(const bf16x8*)ka;
            kn[1] = *(const bf16x8*)(ka + 32);
            const ushort* k2 = kp + (size_t)(npB + lr) * HD + hi * 8;
            kn[2] = *(const bf16x8*)k2;
            kn[3] = *(const bf16x8*)(k2 + 32);
        }
#pragma unroll
        for (int db = 0; db < 4; ++db) {
            const ushort* vp = vtp + (size_t)(db * 16 + lr) * NKV + np + hi * 4;
            vna[db] = *(const bf16x4*)vp;          // g=23: cols 768-783 (valid)
            vnb[db] = *(const bf16x4*)(vp + 16);   // g=23: in-workspace over-read, unused
        }
        __builtin_amdgcn_s_setprio(1);
#pragma unroll
        for (int t = 0; t < NT; ++t) {
            f32x4 sA = {}, sB = {};
            sA = __builtin_amdgcn_mfma_f32_16x16x32_bf16(kc[0], qa0[t], sA, 0, 0, 0);
            sA = __builtin_amdgcn_mfma_f32_16x16x32_bf16(kc[1], qa1[t], sA, 0, 0, 0);
            sB = __builtin_amdgcn_mfma_f32_16x16x32_bf16(kc[2], qa0[t], sB, 0, 0, 0);
            sB = __builtin_amdgcn_mfma_f32_16x16x32_bf16(kc[3], qa1[t], sB, 0, 0, 0);
            float eA0 = fexp2(sA[0]), eA1 = fexp2(sA[1]), eA2 = fexp2(sA[2]), eA3 = fexp2(sA[3]);
            float eB0 = fexp2(sB[0]), eB1 = fexp2(sB[1]), eB2 = fexp2(sB[2]), eB3 = fexp2(sB[3]);
            lsum[t] += ((eA0 + eA1) + (eA2 + eA3)) + ((eB0 + eB1) + (eB2 + eB3));
            union { uint4 w; bf16x8 v; } pk;
            pk.w.x = pk2(eA0, eA1);
            pk.w.y = pk2(eA2, eA3);
            pk.w.z = pk2(eB0, eB1);
            pk.w.w = pk2(eB2, eB3);
#pragma unroll
            for (int db = 0; db < 4; ++db) {
                union { struct { bf16x4 lo, hi_; } s; bf16x8 v; } vf;
                vf.s.lo = vca[db]; vf.s.hi_ = vcb[db];
                oacc[t][db] = __builtin_amdgcn_mfma_f32_16x16x32_bf16(pk.v, vf.v, oacc[t][db], 0, 0, 0);
            }
        }
        __builtin_amdgcn_s_setprio(0);
    };

    for (int gp = 0; gp < 24; gp += 2) {
        gbody(kA, vAa, vAb, kB, vBa, vBb, gp);
        gbody(kB, vBa, vBb, kA, vAa, vAb, gp + 1);
    }

    // tail: nb = 768, rows/cols 768..783 — kA/vAa hold group 24 from the last prefetch
    {
#pragma unroll
        for (int t = 0; t < NT; ++t) {
            f32x4 sA = {};
            sA = __builtin_amdgcn_mfma_f32_16x16x32_bf16(kA[0], qa0[t], sA, 0, 0, 0);
            sA = __builtin_amdgcn_mfma_f32_16x16x32_bf16(kA[1], qa1[t], sA, 0, 0, 0);
            float eA0 = fexp2(sA[0]), eA1 = fexp2(sA[1]), eA2 = fexp2(sA[2]), eA3 = fexp2(sA[3]);
            lsum[t] += (eA0 + eA1) + (eA2 + eA3);
            union { uint4 w; bf16x8 v; } pk;
            pk.w.x = pk2(eA0, eA1);
            pk.w.y = pk2(eA2, eA3);
            pk.w.z = 0;
            pk.w.w = 0;
#pragma unroll
            for (int db = 0; db < 4; ++db) {
                union { struct { bf16x4 lo, hi_; } s; bf16x8 v; } vf;
                vf.s.lo = vAa[db]; vf.s.hi_ = vAa[db];   // hi half multiplied by 0
                oacc[t][db] = __builtin_amdgcn_mfma_f32_16x16x32_bf16(pk.v, vf.v, oacc[t][db], 0, 0, 0);
            }
        }
    }

    // epilogue: lane (hi,lr) has partial row-sum for m=lr; reduce over hi-groups,
    // broadcast to the output fragment rows (m = 4*hi+r), normalize, store.
#pragma unroll
    for (int t = 0; t < NT; ++t) {
        float sum = lsum[t];
        sum += __shfl_xor(sum, 16);
        sum += __shfl_xor(sum, 32);
        float inv = 1.0f / sum;   // valid for row m = lr
#pragma unroll
        for (int r = 0; r < 4; ++r) {
            float invr = __shfl(inv, hi * 4 + r);
            int m = m0 + t * 16 + hi * 4 + r;
            ushort* op = obuf + ((size_t)b * MQ + m) * DIM + h * HD;
#pragma unroll
            for (int db = 0; db < 4; ++db)
                op[db * 16 + lr] = f2bf(oacc[t][db][r] * invr);
        }
    }
}

__global__ __launch_bounds__(128) void attn_k(const ushort* __restrict__ q,
                                              const ushort* __restrict__ kbuf,
                                              const ushort* __restrict__ vt,
                                              ushort* __restrict__ obuf) {
    const int lane = threadIdx.x & 63, wid = threadIdx.x >> 6;
    const int bid = blockIdx.x;
    const int bh = bid % 96;           // bh-major: all mb of one bh share bid%8 -> one XCD
    const int mb = bid / 96;
    const int b = bh / NHEAD, h = bh % NHEAD;
    const ushort* kp  = kbuf + (size_t)bh * NKV * HD;
    const ushort* vtp = vt + (size_t)bh * HD * NKV;
    const int mbase = mb * 112;
    if (wid == 0)
        attn_wave<4>(q, kp, vtp, obuf, bh, b, h, mbase, lane);
    else
        attn_wave<3>(q, kp, vtp, obuf, bh, b, h, mbase + 64, lane);
}

// ---------------- launch ----------------

extern "C" void kernel_launch(void* const* d_in, const int* in_sizes, int n_in,
                              void* d_out, int out_size, void* d_ws, size_t ws_size,
                              hipStream_t stream) {
    const float* s_x  = (const float*)d_in[0];
    const float* t_x  = (const float*)d_in[1];
    const float* csp  = (const float*)d_in[2];
    const float* ctp  = (const float*)d_in[3];
    const float* vsp  = (const float*)d_in[4];
    const float* vtp  = (const float*)d_in[5];
    const float* Wq   = (const float*)d_in[6];
    const float* qb   = (const float*)d_in[7];
    const float* Wkv  = (const float*)d_in[8];
    const float* kvb  = (const float*)d_in[9];
    const float* Wpj  = (const float*)d_in[10];
    const float* pjb  = (const float*)d_in[11];
    float* out = (float*)d_out;

    ushort* w = (ushort*)d_ws;
    ushort* qin  = w; w += (size_t)B_ * MQ * DIM;
    ushort* sb   = w; w += (size_t)B_ * NKV * DIM;
    ushort* wqb  = w; w += (size_t)DIM * DIM;
    ushort* wkvb = w; w += (size_t)2 * DIM * DIM;
    ushort* wpjb = w; w += (size_t)DIM * DIM;
    ushort* qs   = w; w += (size_t)B_ * NHEAD * MQ * HD;
    ushort* kb   = w; w += (size_t)B_ * NHEAD * NKV * HD;
    ushort* vtb  = w; w += (size_t)B_ * NHEAD * HD * NKV;
    ushort* ob   = w; w += (size_t)B_ * MQ * DIM;

    prep_all_k<<<16464, 256, 0, stream>>>(t_x, vsp, vtp, s_x, csp, ctp,
                                          Wq, Wkv, Wpj,
                                          qin, sb, wqb, wkvb, wpjb, out);

    gemm_qkv_k<<<588 + 588, 256, 0, stream>>>(qin, sb, wqb, wkvb, qb, kvb, qs, kb, vtb);

    attn_k<<<1344, 128, 0, stream>>>(qs, kb, vtb, ob);

    gemm_proj_k<<<dim3(DIM / 128, B_ * MQ / 128), 256, 0, stream>>>(ob, wpjb, pjb, out);
}